// Round 1
// baseline (1146.584 us; speedup 1.0000x reference)
//
#include <hip/hip_runtime.h>

// Problem constants (from reference setup_inputs):
//   g=4, s=4096, d=2048 (d unused), num_experts=16, capacity=2*s/16=512
//   out tuple: (scalar 0.0, [4,4096,16,512] f32, same-shape bool)
//   d_out flat layout (all read back as f32):
//     [0]                      : scalar 0.0
//     [1 .. 1+134217728)       : float tensor
//     [1+134217728 .. end)     : bool tensor (write 1.0f/0.0f)
#define TENSOR_ELEMS 134217728LL   // 4*4096*16*512
#define TOTAL_ELEMS  268435457LL   // 1 + 2*TENSOR_ELEMS
#define N_FLOAT4     67108864LL    // 268435456 / 4 (tail of 1 element)

__global__ void rrg_fill_zero(float4* __restrict__ out4, long long n4) {
    long long i = (long long)blockIdx.x * blockDim.x + threadIdx.x;
    const long long stride = (long long)gridDim.x * blockDim.x;
    const float4 z = make_float4(0.f, 0.f, 0.f, 0.f);
    for (; i < n4; i += stride) {
        out4[i] = z;
    }
    // 1-element tail (index 268435456): it is NOT a one-position
    // (t=16383 -> slot needed 255, actual 511), so zero is correct.
    if (blockIdx.x == 0 && threadIdx.x == 0) {
        ((float*)out4)[TOTAL_ELEMS - 1] = 0.0f;
    }
}

__global__ void rrg_set_ones(float* __restrict__ out) {
    // one thread per (g, tok): t in [0, 16384)
    const int t = blockIdx.x * blockDim.x + threadIdx.x;
    const int tok  = t & 4095;       // s = 4096
    const int e    = tok & 15;       // expert = tok % 16
    const int slot = tok >> 4;       // slot   = tok / 16
    const long long idx = (((long long)t * 16) + e) * 512 + slot;
    out[1 + idx] = 1.0f;                  // float tensor
    out[1 + TENSOR_ELEMS + idx] = 1.0f;   // bool tensor (read back as f32)
}

extern "C" void kernel_launch(void* const* d_in, const int* in_sizes, int n_in,
                              void* d_out, int out_size, void* d_ws, size_t ws_size,
                              hipStream_t stream) {
    (void)d_in; (void)in_sizes; (void)n_in; (void)d_ws; (void)ws_size;
    float* out = (float*)d_out;

    // Zero-fill: 67108864 float4 stores. 8192 blocks x 256 thr = 2,097,152
    // threads, 32 float4s each, grid-stride (coalesced 16B/lane).
    rrg_fill_zero<<<8192, 256, 0, stream>>>((float4*)out, N_FLOAT4);

    // Scatter the 2*16384 ones (stream-ordered after the fill).
    rrg_set_ones<<<16384 / 256, 256, 0, stream>>>(out);
}

// Round 2
// 1055.912 us; speedup vs baseline: 1.0859x; 1.0859x over previous
//
#include <hip/hip_runtime.h>

// Problem: g=4, s=4096, num_experts=16, capacity=512.
// Output tuple read back flat as f32:
//   [0]                  scalar 0.0
//   [1 .. 1+N)           float tensor [4,4096,16,512], one-hot
//   [1+N .. 1+2N)        bool tensor, same pattern (1.0f/0.0f)
// N = 4*4096*16*512 = 134217728. Total = 268435457 elements.
//
// One-hot position per (g,tok): a = ((g*4096+tok)*16 + tok%16)*512 + tok/16.
// Inverse from tensor-local index a:
//   slot = a & 511, e = (a>>9)&15, tok = (a>>13)&4095
//   is_one = (e == (tok&15)) && (slot == (tok>>4))
//
// Harness re-poisons d_out to 0xAA before every timed call -> must write
// every element. Single kernel, one float4 store per thread (memory-bound;
// rocclr fillBuffer demonstrates ~6.2 TB/s for this pattern).

#define TENSOR_ELEMS 134217728LL
#define TOTAL_ELEMS  268435457LL
#define N_FLOAT4     67108864     // (TOTAL_ELEMS-1)/4; 1-element tail

__global__ void __launch_bounds__(256) rrg_write(float4* __restrict__ out4) {
    const int i = blockIdx.x * 256 + threadIdx.x;   // [0, 67108864)
    float4 v = make_float4(0.f, 0.f, 0.f, 0.f);
    const long long n0 = 4LL * i;   // flat output element index of lane's base
#pragma unroll
    for (int j = 0; j < 4; ++j) {
        const long long n = n0 + j;
        if (n >= 1) {                       // n==0 is the scalar (0.0)
            long long a = n - 1;            // tensor-local index
            if (a >= TENSOR_ELEMS) a -= TENSOR_ELEMS;   // fold bool region
            const int slot = (int)(a & 511);
            const int e    = (int)((a >> 9) & 15);
            const int tok  = (int)((a >> 13) & 4095);
            if (e == (tok & 15) && slot == (tok >> 4))
                (&v.x)[j] = 1.0f;
        }
    }
    out4[i] = v;
    // tail element 268435456: tensor-B a=134217727 -> slot=511, tok=4095,
    // needed slot=255 -> not a one; write 0.
    if (i == 0)
        ((float*)out4)[TOTAL_ELEMS - 1] = 0.0f;
}

extern "C" void kernel_launch(void* const* d_in, const int* in_sizes, int n_in,
                              void* d_out, int out_size, void* d_ws, size_t ws_size,
                              hipStream_t stream) {
    (void)d_in; (void)in_sizes; (void)n_in; (void)d_ws; (void)ws_size;
    // 67108864 float4 stores / 256 threads = 262144 blocks, 1 store/thread.
    rrg_write<<<N_FLOAT4 / 256, 256, 0, stream>>>((float4*)d_out);
}